// Round 3
// baseline (17331.300 us; speedup 1.0000x reference)
//
#include <hip/hip_runtime.h>
#include <math.h>

#define B 32
#define T 800
#define E 256
#define H 512
#define V 10000
#define S 100
#define VP 10016
#define NBLK 256
#define NT 512

typedef float f4v __attribute__((ext_vector_type(4)));

// ---- workspace float offsets ----
#define OFF_ENCP   512                       // [32][800][512]
#define OFF_XC0    (OFF_ENCP + B*T*512)      // [32][1280]  ping
#define OFF_XC1    (OFF_XC0 + B*1280)        // [32][1280]  pong
#define OFF_YCAT   (OFF_XC1 + B*1280)        // [32][1024]  [z | ctx]
#define OFF_DECC   (OFF_YCAT + B*1024)       // [32][512]
#define OFF_QV     (OFF_DECC + B*512)        // [32][512]
#define OFF_EBUF   (OFF_QV + B*512)          // [32][800]
#define OFF_LP     (OFF_EBUF + B*T)          // [32][10016]

__device__ __forceinline__ float tanh_fast(float x) {
    float e = __expf(2.0f * x);
    return 1.0f - __fdividef(2.0f, e + 1.0f);
}

struct DecArgs {
    const float* encpad; const float* emb; const float* Wih; const float* Whh;
    const float* bih; const float* bhh; const float* Wdec; const float* vatt;
    const float* Wout; const float* bout; const int* enclen;
    float* outp; float* ws;
};

// enc_proj[25600,512] = enc_pad @ W_enc  (once, separate kernel)
__global__ __launch_bounds__(256) void k_encproj(const float* Ap, const float* Wenc, float* outp) {
    __shared__ float Ast[16][68];
    __shared__ float Bs[16][68];
    int rb = blockIdx.x, cb = blockIdx.y;
    int tid = threadIdx.x;
    int tx = tid & 15, ty = tid >> 4;
    float acc[4][4] = {};
    for (int kb = 0; kb < 32; kb++) {
        #pragma unroll
        for (int i = 0; i < 4; i++) {
            int idx = tid + i*256;
            int r = idx >> 4, k = idx & 15;
            Ast[k][r] = Ap[(rb*64 + r)*512 + kb*16 + k];
        }
        #pragma unroll
        for (int i = 0; i < 4; i++) {
            int idx = tid + i*256;
            int k = idx >> 6, c = idx & 63;
            Bs[k][c] = Wenc[(kb*16 + k)*512 + cb*64 + c];
        }
        __syncthreads();
        #pragma unroll
        for (int kk = 0; kk < 16; kk++) {
            f4v a4 = *(const f4v*)&Ast[kk][ty*4];
            f4v b4 = *(const f4v*)&Bs[kk][tx*4];
            #pragma unroll
            for (int i = 0; i < 4; i++)
                #pragma unroll
                for (int j = 0; j < 4; j++)
                    acc[i][j] += a4[i] * b4[j];
        }
        __syncthreads();
    }
    #pragma unroll
    for (int i = 0; i < 4; i++)
        #pragma unroll
        for (int j = 0; j < 4; j++)
            outp[(rb*64 + ty*4 + i)*512 + cb*64 + tx*4 + j] = acc[i][j];
}

// sense-reversing grid barrier: one arrival counter + one epoch word.
// Epoch line mutates ONCE per barrier -> no invalidation storm while polling.
__device__ __forceinline__ void gsync(unsigned* cnt, unsigned* epoch, unsigned e) {
    __syncthreads();
    if (threadIdx.x == 0) {
        __builtin_amdgcn_fence(__ATOMIC_RELEASE, "agent");
        unsigned old = __hip_atomic_fetch_add(cnt, 1u, __ATOMIC_RELAXED, __HIP_MEMORY_SCOPE_AGENT);
        if (old == NBLK - 1) {
            __hip_atomic_store(cnt, 0u, __ATOMIC_RELAXED, __HIP_MEMORY_SCOPE_AGENT);
            __hip_atomic_store(epoch, e, __ATOMIC_RELEASE, __HIP_MEMORY_SCOPE_AGENT);
        } else {
            while (__hip_atomic_load(epoch, __ATOMIC_RELAXED, __HIP_MEMORY_SCOPE_AGENT) < e)
                __builtin_amdgcn_s_sleep(4);
        }
        __builtin_amdgcn_fence(__ATOMIC_ACQUIRE, "agent");
    }
    __syncthreads();
}

__global__ __launch_bounds__(NT) void coop_decoder(DecArgs a) {
    __shared__ float sm[33024];          // 129 KiB, 1 block/CU
    int* smi = (int*)sm;
    const int tid = threadIdx.x;
    const int blk = blockIdx.x;
    unsigned* cnt   = (unsigned*)a.ws;        // word 0
    unsigned* epoch = (unsigned*)a.ws + 32;   // separate 128B line
    float* ycat = a.ws + OFF_YCAT;
    float* decc = a.ws + OFF_DECC;
    float* qv   = a.ws + OFF_QV;
    float* ebuf = a.ws + OFF_EBUF;
    float* lp   = a.ws + OFF_LP;
    const float* encp = a.ws + OFF_ENCP;

    unsigned e = 1;

    // ---- init: xbuf0 = [emb(BOS) | 0 | 0], decc = 0
    if (blk < 32) {
        float* xb0 = a.ws + OFF_XC0;
        int b = blk;
        if (tid < 256) xb0[b*1280 + tid] = a.emb[1*E + tid];
        xb0[b*1280 + 256 + tid] = 0.f;
        xb0[b*1280 + 768 + tid] = 0.f;
        decc[b*512 + tid] = 0.f;
    }
    gsync(cnt, epoch, e++);

    for (int s = 0; s < S; s++) {
        const float* xb  = a.ws + ((s & 1) ? OFF_XC1 : OFF_XC0);  // read this step
        float*       xbn = a.ws + ((s & 1) ? OFF_XC0 : OFF_XC1);  // write for next step

        // ===== phase A: gates + LSTM. 128 blocks, 4 h each; rows = 4 gates x 4 h.
        // W global->reg (single-use), x in LDS [32][644], 8 k-split waves, LDS reduce.
        if (blk < 128) {
            const int h0 = blk*4;
            const int l = tid & 63, wid = tid >> 6;   // wid = k-split
            const int vq = l >> 4, bq = l & 15;       // vq = gate, bq -> 2 b's
            float acc[4][2] = {{0.f,0.f},{0.f,0.f},{0.f,0.f},{0.f,0.f}};
            for (int half = 0; half < 2; half++) {
                {   // stage x half [32][640] -> stride 644
                    int sb = tid >> 4, c0 = tid & 15;
                    const f4v* src = (const f4v*)&xb[sb*1280 + half*640];
                    #pragma unroll
                    for (int it = 0; it < 10; it++) {
                        int c4 = c0 + it*16;
                        *(f4v*)&sm[sb*644 + 4*c4] = src[c4];
                    }
                }
                __syncthreads();
                const int kb = wid*80;
                #pragma unroll 2
                for (int g = 0; g < 20; g++) {
                    int kk = half*640 + kb + g*4;
                    f4v w[4];
                    if (kk < 768) {
                        #pragma unroll
                        for (int i = 0; i < 4; i++)
                            w[i] = *(const f4v*)&a.Wih[(vq*512 + h0 + i)*768 + kk];
                    } else {
                        #pragma unroll
                        for (int i = 0; i < 4; i++)
                            w[i] = *(const f4v*)&a.Whh[(vq*512 + h0 + i)*512 + kk - 768];
                    }
                    #pragma unroll
                    for (int j = 0; j < 2; j++) {
                        f4v x4 = *(const f4v*)&sm[(bq + 16*j)*644 + kb + g*4];
                        #pragma unroll
                        for (int i = 0; i < 4; i++)
                            acc[i][j] += w[i][0]*x4[0] + w[i][1]*x4[1] + w[i][2]*x4[2] + w[i][3]*x4[3];
                    }
                }
                __syncthreads();
            }
            // partial [8][16][33] @ 20608
            #pragma unroll
            for (int i = 0; i < 4; i++)
                #pragma unroll
                for (int j = 0; j < 2; j++)
                    sm[20608 + wid*528 + (vq*4 + i)*33 + bq + 16*j] = acc[i][j];
            __syncthreads();
            if (tid < 128) {
                int hl = tid >> 5, b = tid & 31;
                int h = h0 + hl;
                float gv[4];
                #pragma unroll
                for (int g2 = 0; g2 < 4; g2++) {
                    float s2 = 0.f;
                    #pragma unroll
                    for (int w2 = 0; w2 < 8; w2++)
                        s2 += sm[20608 + w2*528 + (g2*4 + hl)*33 + b];
                    gv[g2] = s2 + a.bih[g2*512 + h] + a.bhh[g2*512 + h];
                }
                float ig = 1.f/(1.f + expf(-gv[0]));
                float fg = 1.f/(1.f + expf(-gv[1]));
                float gg = tanhf(gv[2]);
                float og = 1.f/(1.f + expf(-gv[3]));
                float c = fg*decc[b*512 + h] + ig*gg;
                decc[b*512 + h] = c;
                float z = og*tanhf(c);
                ycat[b*1024 + h] = z;
                xbn[b*1280 + 768 + h] = z;    // z for NEXT step (ping-pong: no race)
            }
        }
        gsync(cnt, epoch, e++);

        // ===== phase B: q = z @ W_dec. 16 blocks x 32 a. waves = (a-sub2, ksplit4).
        if (blk < 16) {
            const int a0 = blk*32;
            const int l = tid & 63, wid = tid >> 6;
            const int as = wid >> 2, ks = wid & 3;
            const int aq = l >> 4, bq = l & 15;
            {   // stage z [32][512] -> stride 516
                int sb = tid >> 4, c0 = tid & 15;
                const f4v* src = (const f4v*)&ycat[sb*1024];
                #pragma unroll
                for (int it = 0; it < 8; it++) {
                    int c4 = c0 + it*16;
                    *(f4v*)&sm[sb*516 + 4*c4] = src[c4];
                }
            }
            __syncthreads();
            float acc[4][2] = {{0.f,0.f},{0.f,0.f},{0.f,0.f},{0.f,0.f}};
            const int kb = ks*128;
            #pragma unroll 2
            for (int g = 0; g < 32; g++) {
                f4v wv[4];
                #pragma unroll
                for (int kk = 0; kk < 4; kk++)
                    wv[kk] = *(const f4v*)&a.Wdec[(kb + g*4 + kk)*512 + a0 + as*16 + aq*4];
                #pragma unroll
                for (int j = 0; j < 2; j++) {
                    f4v x4 = *(const f4v*)&sm[(bq + 16*j)*516 + kb + g*4];
                    #pragma unroll
                    for (int i = 0; i < 4; i++)
                        acc[i][j] += wv[0][i]*x4[0] + wv[1][i]*x4[1] + wv[2][i]*x4[2] + wv[3][i]*x4[3];
                }
            }
            #pragma unroll
            for (int i = 0; i < 4; i++)
                #pragma unroll
                for (int j = 0; j < 2; j++)
                    sm[16512 + wid*528 + (aq*4 + i)*33 + bq + 16*j] = acc[i][j];
            __syncthreads();
            for (int o = tid; o < 1024; o += NT) {
                int al = o >> 5, b = o & 31;
                int as2 = al >> 4;
                float qs = 0.f;
                #pragma unroll
                for (int k2 = 0; k2 < 4; k2++)
                    qs += sm[16512 + (as2*4 + k2)*528 + (al & 15)*33 + b];
                qv[b*512 + a0 + al] = qs;
            }
        }
        gsync(cnt, epoch, e++);

        // ===== phase C: e[b,t] = tanh(encp + q) . v_att. 256 blocks (b x t-slice).
        {
            int b = blk >> 3, sl = blk & 7;
            int len = a.enclen[b];
            int t0 = sl*100;
            if (t0 < len) {
                sm[tid] = qv[b*512 + tid];
                sm[512 + tid] = a.vatt[tid];
                __syncthreads();
                int wid = tid >> 6, lane = tid & 63;
                int tend = min(t0 + 100, len);
                for (int t = t0 + wid; t < tend; t += 8) {
                    const f4v* row = (const f4v*)&encp[(b*800 + t)*512];
                    float accd = 0.f;
                    #pragma unroll
                    for (int i2 = 0; i2 < 2; i2++) {
                        int u = lane + 64*i2;
                        f4v ep = row[u];
                        f4v q4 = *(const f4v*)&sm[4*u];
                        f4v vv = *(const f4v*)&sm[512 + 4*u];
                        accd += tanh_fast(ep[0] + q4[0])*vv[0];
                        accd += tanh_fast(ep[1] + q4[1])*vv[1];
                        accd += tanh_fast(ep[2] + q4[2])*vv[2];
                        accd += tanh_fast(ep[3] + q4[3])*vv[3];
                    }
                    #pragma unroll
                    for (int off = 32; off >= 1; off >>= 1)
                        accd += __shfl_xor(accd, off, 64);
                    if (lane == 0) ebuf[b*800 + t] = accd;
                }
            }
        }
        gsync(cnt, epoch, e++);

        // ===== phase DE: softmax (replicated per d-slice) + context. 256 blocks.
        {
            int b = blk >> 3, dsl = blk & 7;
            int len = a.enclen[b];
            int d0 = dsl*64;
            float m = -3.0e38f;
            for (int t = tid; t < len; t += NT) m = fmaxf(m, ebuf[b*800 + t]);
            sm[1024 + tid] = m;
            __syncthreads();
            for (int st = 256; st >= 1; st >>= 1) {
                if (tid < st) sm[1024 + tid] = fmaxf(sm[1024 + tid], sm[1024 + tid + st]);
                __syncthreads();
            }
            float M = sm[1024];
            __syncthreads();
            float ssum = 0.f;
            for (int t = tid; t < len; t += NT) {
                float p = expf(ebuf[b*800 + t] - M);
                sm[t] = p;
                ssum += p;
            }
            sm[1024 + tid] = ssum;
            __syncthreads();
            for (int st = 256; st >= 1; st >>= 1) {
                if (tid < st) sm[1024 + tid] += sm[1024 + tid + st];
                __syncthreads();
            }
            float inv = 1.f / sm[1024];
            {   // attention-weight output slice (reuse dsl as t-slice)
                int t0 = dsl*100;
                float* wrow = a.outp + 2*B*S + (size_t)(b*S + s)*T;
                for (int t = t0 + tid; t < t0 + 100; t += NT)
                    wrow[t] = (t < len) ? sm[t]*inv : 0.f;
            }
            {   // context for this 64-wide d-slice
                int d = tid & 63, ts = tid >> 6;
                float accd = 0.f;
                for (int t = ts; t < len; t += 8)
                    accd += sm[t] * a.encpad[(b*800 + t)*512 + d0 + d];
                accd *= inv;
                __syncthreads();
                sm[1536 + ts*68 + d] = accd;
                __syncthreads();
                if (tid < 64) {
                    float c = 0.f;
                    #pragma unroll
                    for (int t2 = 0; t2 < 8; t2++) c += sm[1536 + t2*68 + tid];
                    ycat[b*1024 + 512 + d0 + tid] = c;
                    xbn[b*1280 + 256 + d0 + tid] = c;   // ctx for NEXT step
                }
            }
        }
        gsync(cnt, epoch, e++);

        // ===== phase F: logits. 250 blocks x 40 v. waves = 8 k-split.
        // W_out global->reg; ycat [32][1028] LDS; tile [5v][4b] => 80 FMA / 4 LDS.
        if (blk < 250) {
            const int v0 = blk*40;
            const int l = tid & 63, wid = tid >> 6;
            const int vq = l & 7, bq = l >> 3;
            {   // stage ycat [32][1024] -> stride 1028
                int sb = tid >> 4, c0 = tid & 15;
                const f4v* src = (const f4v*)&ycat[sb*1024];
                #pragma unroll
                for (int it = 0; it < 16; it++) {
                    int c4 = c0 + it*16;
                    *(f4v*)&sm[sb*1028 + 4*c4] = src[c4];
                }
            }
            __syncthreads();
            float acc[5][4] = {};
            const int kb = wid*128;
            const float* wbase = &a.Wout[(v0 + vq*5)*1024 + kb];
            #pragma unroll 2
            for (int g = 0; g < 32; g++) {
                f4v w[5];
                #pragma unroll
                for (int i = 0; i < 5; i++)
                    w[i] = *(const f4v*)&wbase[i*1024 + g*4];
                #pragma unroll
                for (int j = 0; j < 4; j++) {
                    f4v x4 = *(const f4v*)&sm[(bq + 8*j)*1028 + kb + g*4];
                    #pragma unroll
                    for (int i = 0; i < 5; i++)
                        acc[i][j] += w[i][0]*x4[0] + w[i][1]*x4[1] + w[i][2]*x4[2] + w[i][3]*x4[3];
                }
            }
            __syncthreads();          // all x reads done
            // partial [8][40][33] overlays x region
            #pragma unroll
            for (int i = 0; i < 5; i++)
                #pragma unroll
                for (int j = 0; j < 4; j++)
                    sm[wid*1320 + (vq*5 + i)*33 + bq + 8*j] = acc[i][j];
            __syncthreads();
            for (int o = tid; o < 1280; o += NT) {
                int r = o >> 5, b = o & 31;
                float val = a.bout[v0 + r];
                #pragma unroll
                for (int w2 = 0; w2 < 8; w2++)
                    val += sm[w2*1320 + r*33 + b];
                lp[b*VP + v0 + r] = val;
            }
        }
        gsync(cnt, epoch, e++);

        // ===== phase G: argmax + log-softmax + embedding feedback. 32 blocks.
        if (blk < 32) {
            int b = blk;
            float lv[20];
            float lmax = -3.0e38f; int lidx = 0x7fffffff;
            #pragma unroll
            for (int it = 0; it < 20; it++) {
                int v = it*NT + tid;
                float x = (v < V) ? lp[b*VP + v] : -3.0e38f;
                lv[it] = x;
                if (x > lmax) { lmax = x; lidx = v; }
            }
            sm[tid] = lmax; smi[512 + tid] = lidx;
            __syncthreads();
            for (int st = 256; st >= 1; st >>= 1) {
                if (tid < st) {
                    float ov = sm[tid + st]; int oi = smi[512 + tid + st];
                    if (ov > sm[tid] || (ov == sm[tid] && oi < smi[512 + tid])) {
                        sm[tid] = ov; smi[512 + tid] = oi;
                    }
                }
                __syncthreads();
            }
            float M = sm[0]; int am = smi[512];
            __syncthreads();
            float ssum = 0.f;
            #pragma unroll
            for (int it = 0; it < 20; it++) ssum += expf(lv[it] - M);
            sm[tid] = ssum;
            __syncthreads();
            for (int st = 256; st >= 1; st >>= 1) {
                if (tid < st) sm[tid] += sm[tid + st];
                __syncthreads();
            }
            if (tid == 0) {
                a.outp[b*S + s] = -logf(sm[0]);
                a.outp[B*S + b*S + s] = (float)am;
            }
            if (tid < 256) xbn[b*1280 + tid] = a.emb[(size_t)am*E + tid];
        }
        gsync(cnt, epoch, e++);
    }
}

extern "C" void kernel_launch(void* const* d_in, const int* in_sizes, int n_in,
                              void* d_out, int out_size, void* d_ws, size_t ws_size,
                              hipStream_t stream) {
    (void)in_sizes; (void)n_in; (void)out_size; (void)ws_size;
    const float* encpad = (const float*)d_in[0];
    const float* emb    = (const float*)d_in[1];
    const float* Wih    = (const float*)d_in[2];
    const float* Whh    = (const float*)d_in[3];
    const float* bih    = (const float*)d_in[4];
    const float* bhh    = (const float*)d_in[5];
    const float* Wenc   = (const float*)d_in[6];
    const float* Wdec   = (const float*)d_in[7];
    const float* vatt   = (const float*)d_in[8];
    const float* Wout   = (const float*)d_in[9];
    const float* bout   = (const float*)d_in[10];
    const int*   enclen = (const int*)d_in[11];
    float* outp = (float*)d_out;
    float* ws   = (float*)d_ws;

    hipMemsetAsync(d_ws, 0, 2048, stream);   // barrier counter + epoch

    k_encproj<<<dim3(400, 8), 256, 0, stream>>>(encpad, Wenc, ws + OFF_ENCP);

    DecArgs args = { encpad, emb, Wih, Whh, bih, bhh, Wdec, vatt, Wout, bout,
                     enclen, outp, ws };
    void* kp[] = { &args };
    hipLaunchCooperativeKernel((const void*)coop_decoder, dim3(NBLK), dim3(NT),
                               kp, 0, stream);
}

// Round 4
// 16620.589 us; speedup vs baseline: 1.0428x; 1.0428x over previous
//
#include <hip/hip_runtime.h>
#include <math.h>

#define B 32
#define T 800
#define E 256
#define H 512
#define V 10000
#define S 100

typedef float f4 __attribute__((ext_vector_type(4)));

// ---- workspace float offsets ----
#define OFF_ENCP 0                         // [32][800][512]
#define OFF_GATES (OFF_ENCP + B*T*512)     // [32][2048]
#define OFF_ZB   (OFF_GATES + B*2048)      // [32][512]  z_{s-1} (single buf, stream-ordered)
#define OFF_CB   (OFF_ZB + B*512)          // [32][512]  ctx_{s-1}
#define OFF_DECC (OFF_CB + B*512)          // [2][32][512] parity (intra-kernel redundant reads)
#define OFF_Q    (OFF_DECC + 2*B*512)      // [32][512]
#define OFF_PB   (OFF_Q + B*512)           // [32][800]  p = exp(e) (ref 0)
#define OFF_PSL  (OFF_PB + B*800)          // [32][8]    per-t-slice partial sums
#define OFF_YC   (OFF_PSL + B*8)           // [32][1024] [z | ctx]
#define OFF_KEY  (OFF_YC + B*1024)         // [2][32] u64 packed (mono(lmax), ~idx)
#define OFF_ESUM (OFF_KEY + 128)           // [2][32] sum exp(l)

__device__ __forceinline__ float tanh_fast(float x) {
    float e = __expf(2.0f * x);
    return 1.0f - __fdividef(2.0f, e + 1.0f);
}

// enc_proj = enc_pad @ W_enc (once)
__global__ __launch_bounds__(256) void k_encproj(const float* Ap, const float* Wenc, float* outp) {
    __shared__ float Ast[16][68];
    __shared__ float Bs[16][68];
    int rb = blockIdx.x, cb = blockIdx.y;
    int tid = threadIdx.x;
    int tx = tid & 15, ty = tid >> 4;
    float acc[4][4] = {};
    for (int kb = 0; kb < 32; kb++) {
        #pragma unroll
        for (int i = 0; i < 4; i++) {
            int idx = tid + i*256;
            int r = idx >> 4, k = idx & 15;
            Ast[k][r] = Ap[(rb*64 + r)*512 + kb*16 + k];
        }
        #pragma unroll
        for (int i = 0; i < 4; i++) {
            int idx = tid + i*256;
            int k = idx >> 6, c = idx & 63;
            Bs[k][c] = Wenc[(kb*16 + k)*512 + cb*64 + c];
        }
        __syncthreads();
        #pragma unroll
        for (int kk = 0; kk < 16; kk++) {
            f4 a4 = *(const f4*)&Ast[kk][ty*4];
            f4 b4 = *(const f4*)&Bs[kk][tx*4];
            #pragma unroll
            for (int i = 0; i < 4; i++)
                #pragma unroll
                for (int j = 0; j < 4; j++)
                    acc[i][j] += a4[i] * b4[j];
        }
        __syncthreads();
    }
    #pragma unroll
    for (int i = 0; i < 4; i++)
        #pragma unroll
        for (int j = 0; j < 4; j++)
            outp[(rb*64 + ty*4 + i)*512 + cb*64 + tx*4 + j] = acc[i][j];
}

__global__ __launch_bounds__(512) void k_init(float* ws) {
    int idx = blockIdx.x*512 + threadIdx.x;   // 32 blocks -> 16384
    ws[OFF_ZB + idx] = 0.f;
    ws[OFF_CB + idx] = 0.f;
    ws[OFF_DECC + B*512 + idx] = 0.f;         // decc[1]
    if (blockIdx.x == 0 && threadIdx.x < 32) {
        unsigned long long* key = (unsigned long long*)(ws + OFF_KEY);
        key[32 + threadIdx.x] = 0xFFFFFFFEull;   // slot[1]: pred = BOS = 1
    }
}

// K0: gates[b][2048] = x @ [Wih|Whh]^T + biases. 128 blocks x 16 j-rows.
// Also: finalize step s-1 (preds/ys outputs), zero step-s accumulators.
__global__ __launch_bounds__(512) void k0_gates(const float* __restrict__ Wih,
    const float* __restrict__ Whh, const float* __restrict__ bih,
    const float* __restrict__ bhh, const float* __restrict__ emb,
    float* __restrict__ ws, float* __restrict__ outp, int s) {
    __shared__ float xs[32*644];
    __shared__ float wsm[16*644];
    __shared__ float part[16*528];
    __shared__ int preds[32];
    const int tid = threadIdx.x, blk = blockIdx.x;
    const int p = s & 1;
    unsigned long long* keys = (unsigned long long*)(ws + OFF_KEY);
    float* esum = ws + OFF_ESUM;
    if (tid < 32) {
        unsigned long long k = keys[(p^1)*32 + tid];
        int pr = (int)(0xFFFFFFFFu - (unsigned)(k & 0xFFFFFFFFull));
        preds[tid] = pr;
        if (blk == 0) {
            if (s > 0) {
                unsigned mu = (unsigned)(k >> 32);
                unsigned ou = (mu & 0x80000000u) ? (mu & 0x7FFFFFFFu) : ~mu;
                float lmax = __uint_as_float(ou);
                outp[tid*S + (s-1)] = lmax - logf(esum[(p^1)*32 + tid]);
                outp[B*S + tid*S + (s-1)] = (float)pr;
            }
            keys[p*32 + tid] = 0ull;
            esum[p*32 + tid] = 0.f;
        }
    }
    __syncthreads();
    const float* zbuf = ws + OFF_ZB;
    const float* cbuf = ws + OFF_CB;
    const int bq = tid & 7, jq = (tid >> 3) & 3, kq = tid >> 5;
    float acc[4][4] = {};
    for (int kh = 0; kh < 2; kh++) {
        for (int i = 0; i < 10; i++) {            // stage x half [32][640]
            int q = tid + i*512;
            int b = q / 160, qq = q - b*160;
            int k = kh*640 + qq*4;
            f4 v;
            if (k < 256)      v = *(const f4*)&emb[(size_t)preds[b]*E + k];
            else if (k < 768) v = *(const f4*)&cbuf[b*512 + (k-256)];
            else              v = *(const f4*)&zbuf[b*512 + (k-768)];
            *(f4*)&xs[b*644 + qq*4] = v;
        }
        for (int i = 0; i < 5; i++) {             // stage W half [16][640]
            int q = tid + i*512;
            int r = q / 160, qq = q - r*160;
            int k = kh*640 + qq*4;
            int j = blk*16 + r;
            f4 v = (k < 768) ? *(const f4*)&Wih[j*768 + k]
                             : *(const f4*)&Whh[j*512 + (k-768)];
            *(f4*)&wsm[r*644 + qq*4] = v;
        }
        __syncthreads();
        #pragma unroll
        for (int it = 0; it < 10; it++) {
            int k = kq*40 + it*4;
            f4 wv[4], xv[4];
            #pragma unroll
            for (int j = 0; j < 4; j++) wv[j] = *(const f4*)&wsm[(jq*4+j)*644 + k];
            #pragma unroll
            for (int i = 0; i < 4; i++) xv[i] = *(const f4*)&xs[(bq+8*i)*644 + k];
            #pragma unroll
            for (int j = 0; j < 4; j++)
                #pragma unroll
                for (int i = 0; i < 4; i++)
                    acc[j][i] += wv[j][0]*xv[i][0] + wv[j][1]*xv[i][1]
                               + wv[j][2]*xv[i][2] + wv[j][3]*xv[i][3];
        }
        __syncthreads();
    }
    #pragma unroll
    for (int j = 0; j < 4; j++)
        #pragma unroll
        for (int i = 0; i < 4; i++)
            part[kq*528 + (jq*4+j)*33 + (bq+8*i)] = acc[j][i];
    __syncthreads();
    {
        int jl = tid >> 5, b = tid & 31;
        int j = blk*16 + jl;
        float g = bih[j] + bhh[j];
        #pragma unroll
        for (int k2 = 0; k2 < 16; k2++) g += part[k2*528 + jl*33 + b];
        ws[OFF_GATES + b*2048 + j] = g;
    }
}

// K1: LSTM pointwise (redundant per block) + q-slice = z @ Wdec[:, a-slice]. 32 blocks.
__global__ __launch_bounds__(512) void k1_lstmq(const float* __restrict__ Wdec,
    float* __restrict__ ws, int s) {
    __shared__ float zs[32*516];
    __shared__ float wds[512*20];
    __shared__ float part[16*528];
    const int tid = threadIdx.x, blk = blockIdx.x;
    const int p = s & 1;
    const float* gates = ws + OFF_GATES;
    const float* dold = ws + OFF_DECC + (p^1)*B*512;
    float* dnew = ws + OFF_DECC + p*B*512;
    {
        int h = tid;
        for (int b = 0; b < 32; b++) {
            const float* g = &gates[b*2048];
            float gi = g[h], gf = g[512+h], gg = g[1024+h], go = g[1536+h];
            float ig = 1.f/(1.f+expf(-gi)), fg = 1.f/(1.f+expf(-gf));
            float g2 = tanhf(gg), og = 1.f/(1.f+expf(-go));
            float c = fg*dold[b*512+h] + ig*g2;
            float z = og*tanhf(c);
            zs[b*516 + h] = z;
            if (blk == 0) {
                dnew[b*512+h] = c;
                ws[OFF_ZB + b*512+h] = z;
                ws[OFF_YC + b*1024 + h] = z;
            }
        }
    }
    const int a0 = blk*16;
    for (int i = 0; i < 4; i++) {             // stage Wdec[:, a0:a0+16]
        int q = tid + i*512;
        int r = q >> 2, c4 = (q & 3)*4;
        *(f4*)&wds[r*20 + c4] = *(const f4*)&Wdec[r*512 + a0 + c4];
    }
    __syncthreads();
    const int bq = tid & 7, aq = (tid >> 3) & 3, kq = tid >> 5;
    float acc[4][4] = {};
    #pragma unroll
    for (int it = 0; it < 8; it++) {
        int k = kq*32 + it*4;
        f4 zv[4], wv[4];
        #pragma unroll
        for (int i = 0; i < 4; i++) zv[i] = *(const f4*)&zs[(bq+8*i)*516 + k];
        #pragma unroll
        for (int kk = 0; kk < 4; kk++) wv[kk] = *(const f4*)&wds[(k+kk)*20 + aq*4];
        #pragma unroll
        for (int j = 0; j < 4; j++)
            #pragma unroll
            for (int i = 0; i < 4; i++)
                acc[j][i] += wv[0][j]*zv[i][0] + wv[1][j]*zv[i][1]
                           + wv[2][j]*zv[i][2] + wv[3][j]*zv[i][3];
    }
    #pragma unroll
    for (int j = 0; j < 4; j++)
        #pragma unroll
        for (int i = 0; i < 4; i++)
            part[kq*528 + (aq*4+j)*33 + (bq+8*i)] = acc[j][i];
    __syncthreads();
    {
        int al = tid >> 5, b = tid & 31;
        float qs = 0.f;
        #pragma unroll
        for (int k2 = 0; k2 < 16; k2++) qs += part[k2*528 + al*33 + b];
        ws[OFF_Q + b*512 + a0 + al] = qs;
    }
}

// K2: p[b,t] = exp(e[b,t]) (ref 0). 256 blocks = b x t-slice(100).
__global__ __launch_bounds__(512) void k2_e(const float* __restrict__ vatt,
    const int* __restrict__ enclen, float* __restrict__ ws) {
    __shared__ float qs[512];
    __shared__ float vs[512];
    __shared__ float wp[8];
    const int tid = threadIdx.x;
    const int b = blockIdx.x >> 3, ts = blockIdx.x & 7;
    const int len = enclen[b];
    const int t0 = ts*100;
    qs[tid] = ws[OFF_Q + b*512 + tid];
    vs[tid] = vatt[tid];
    __syncthreads();
    const int wid = tid >> 6, lane = tid & 63;
    const f4* encp4 = (const f4*)(ws + OFF_ENCP);
    float* pbuf = ws + OFF_PB + b*800;
    float psum = 0.f;
    for (int t = t0 + wid; t < t0 + 100; t += 8) {
        float accd = 0.f;
        if (t < len) {
            const f4* row = &encp4[(size_t)(b*800 + t)*128];
            #pragma unroll
            for (int i = 0; i < 2; i++) {
                int u = lane + 64*i;
                f4 ep = row[u];
                f4 q4 = *(const f4*)&qs[4*u];
                f4 vv = *(const f4*)&vs[4*u];
                accd += tanh_fast(ep[0]+q4[0])*vv[0];
                accd += tanh_fast(ep[1]+q4[1])*vv[1];
                accd += tanh_fast(ep[2]+q4[2])*vv[2];
                accd += tanh_fast(ep[3]+q4[3])*vv[3];
            }
            #pragma unroll
            for (int off = 32; off >= 1; off >>= 1) accd += __shfl_xor(accd, off, 64);
        }
        if (lane == 0) {
            float pv = (t < len) ? __expf(accd) : 0.f;
            pbuf[t] = pv;
            psum += pv;
        }
    }
    if (lane == 0) wp[wid] = psum;
    __syncthreads();
    if (tid == 0) {
        float sum = 0.f;
        #pragma unroll
        for (int i = 0; i < 8; i++) sum += wp[i];
        ws[OFF_PSL + b*8 + ts] = sum;
    }
}

// K3: ctx d-slice + attention-weight output. 256 blocks = b x d-slice(64).
__global__ __launch_bounds__(512) void k3_ctx(const float* __restrict__ encpad,
    const int* __restrict__ enclen, float* __restrict__ ws,
    float* __restrict__ outp, int s) {
    __shared__ float pl[800];
    __shared__ float part[8*68];
    __shared__ float psumsh;
    const int tid = threadIdx.x;
    const int b = blockIdx.x >> 3, dsl = blockIdx.x & 7;
    const int len = enclen[b];
    const int d0 = dsl*64;
    for (int t = tid; t < 800; t += 512) pl[t] = ws[OFF_PB + b*800 + t];
    if (tid == 0) {
        float s2 = 0.f;
        #pragma unroll
        for (int i = 0; i < 8; i++) s2 += ws[OFF_PSL + b*8 + i];
        psumsh = s2;
    }
    __syncthreads();
    float inv = 1.f / psumsh;
    const int lane = tid & 63, tq = tid >> 6;
    float accd = 0.f;
    for (int t = tq; t < len; t += 8)
        accd += pl[t] * encpad[((size_t)(b*800 + t))*512 + d0 + lane];
    part[tq*68 + lane] = accd;
    __syncthreads();
    if (tid < 64) {
        float c = 0.f;
        #pragma unroll
        for (int i = 0; i < 8; i++) c += part[i*68 + tid];
        c *= inv;
        ws[OFF_YC + b*1024 + 512 + d0 + tid] = c;
        ws[OFF_CB + b*512 + d0 + tid] = c;
    }
    if (dsl == 0) {
        float* wrow = outp + 2*B*S + (size_t)(b*S + s)*T;
        for (int t = tid; t < 800; t += 512) wrow[t] = pl[t]*inv;
    }
}

// K4: logits 40 v-rows x 32 b per block (250 blocks), fused argmax/sumexp atomics.
__global__ __launch_bounds__(512) void k4_logits(const float* __restrict__ Wout,
    const float* __restrict__ bout, float* __restrict__ ws, int s) {
    __shared__ float sm[32*1028];
    const int tid = threadIdx.x, blk = blockIdx.x;
    const int p = s & 1;
    const int v0 = blk*40;
    for (int i = 0; i < 17; i++) {
        int q = tid + i*512;
        if (q < 8224) {
            int b = q >> 8, qq = q & 255;
            *(f4*)&sm[b*1028 + qq*4] = *(const f4*)&ws[OFF_YC + b*1024 + qq*4];
        }
    }
    __syncthreads();
    const int wid = tid >> 6, l = tid & 63;
    const int vq = l & 7, bq2 = l >> 3;
    float acc[5][4] = {};
    const int kb = wid*128;
    const float* wbase = &Wout[(size_t)(v0 + vq*5)*1024 + kb];
    #pragma unroll 2
    for (int g = 0; g < 32; g++) {
        f4 w[5];
        #pragma unroll
        for (int i = 0; i < 5; i++) w[i] = *(const f4*)&wbase[i*1024 + g*4];
        #pragma unroll
        for (int j = 0; j < 4; j++) {
            f4 x4 = *(const f4*)&sm[(bq2+8*j)*1028 + kb + g*4];
            #pragma unroll
            for (int i = 0; i < 5; i++)
                acc[i][j] += w[i][0]*x4[0] + w[i][1]*x4[1] + w[i][2]*x4[2] + w[i][3]*x4[3];
        }
    }
    __syncthreads();
    #pragma unroll
    for (int i = 0; i < 5; i++)
        #pragma unroll
        for (int j = 0; j < 4; j++)
            sm[wid*1320 + (vq*5+i)*33 + (bq2+8*j)] = acc[i][j];
    __syncthreads();
    if (tid < 256) {
        int b = tid >> 3, u = tid & 7;
        float bmax = -3.0e38f; int bidx = 0; float bsum = 0.f;
        #pragma unroll
        for (int i = 0; i < 5; i++) {
            int r = u*5 + i;
            float lv = bout[v0 + r];
            #pragma unroll
            for (int w2 = 0; w2 < 8; w2++) lv += sm[w2*1320 + r*33 + b];
            bsum += __expf(lv);
            if (lv > bmax) { bmax = lv; bidx = v0 + r; }
        }
        #pragma unroll
        for (int off = 1; off < 8; off <<= 1) {
            float ov = __shfl_xor(bmax, off, 64);
            int oi = __shfl_xor(bidx, off, 64);
            float os = __shfl_xor(bsum, off, 64);
            bsum += os;
            if (ov > bmax || (ov == bmax && oi < bidx)) { bmax = ov; bidx = oi; }
        }
        if (u == 0) {
            unsigned mu = __float_as_uint(bmax);
            mu = (mu & 0x80000000u) ? ~mu : (mu | 0x80000000u);
            unsigned long long kk = ((unsigned long long)mu << 32)
                                  | (unsigned long long)(0xFFFFFFFFu - (unsigned)bidx);
            atomicMax((unsigned long long*)(ws + OFF_KEY) + p*32 + b, kk);
            atomicAdd(ws + OFF_ESUM + p*32 + b, bsum);
        }
    }
}

__global__ __launch_bounds__(64) void k5_final(float* __restrict__ ws, float* __restrict__ outp) {
    int b = threadIdx.x;
    if (b < 32) {
        unsigned long long k = ((unsigned long long*)(ws + OFF_KEY))[32 + b];  // p = 99&1 = 1
        unsigned mu = (unsigned)(k >> 32);
        unsigned ou = (mu & 0x80000000u) ? (mu & 0x7FFFFFFFu) : ~mu;
        int pr = (int)(0xFFFFFFFFu - (unsigned)(k & 0xFFFFFFFFull));
        outp[b*S + 99] = __uint_as_float(ou) - logf(ws[OFF_ESUM + 32 + b]);
        outp[B*S + b*S + 99] = (float)pr;
    }
}

extern "C" void kernel_launch(void* const* d_in, const int* in_sizes, int n_in,
                              void* d_out, int out_size, void* d_ws, size_t ws_size,
                              hipStream_t stream) {
    (void)in_sizes; (void)n_in; (void)out_size; (void)ws_size;
    const float* encpad = (const float*)d_in[0];
    const float* emb    = (const float*)d_in[1];
    const float* Wih    = (const float*)d_in[2];
    const float* Whh    = (const float*)d_in[3];
    const float* bih    = (const float*)d_in[4];
    const float* bhh    = (const float*)d_in[5];
    const float* Wenc   = (const float*)d_in[6];
    const float* Wdec   = (const float*)d_in[7];
    const float* vatt   = (const float*)d_in[8];
    const float* Wout   = (const float*)d_in[9];
    const float* bout   = (const float*)d_in[10];
    const int*   enclen = (const int*)d_in[11];
    float* outp = (float*)d_out;
    float* ws   = (float*)d_ws;

    k_init<<<32, 512, 0, stream>>>(ws);
    k_encproj<<<dim3(400, 8), 256, 0, stream>>>(encpad, Wenc, ws + OFF_ENCP);

    for (int s = 0; s < S; s++) {
        k0_gates<<<128, 512, 0, stream>>>(Wih, Whh, bih, bhh, emb, ws, outp, s);
        k1_lstmq<<<32, 512, 0, stream>>>(Wdec, ws, s);
        k2_e<<<256, 512, 0, stream>>>(vatt, enclen, ws);
        k3_ctx<<<256, 512, 0, stream>>>(encpad, enclen, ws, outp, s);
        k4_logits<<<250, 512, 0, stream>>>(Wout, bout, ws, s);
    }
    k5_final<<<1, 64, 0, stream>>>(ws, outp);
}

// Round 5
// 9939.359 us; speedup vs baseline: 1.7437x; 1.6722x over previous
//
#include <hip/hip_runtime.h>
#include <math.h>

#define B 32
#define T 800
#define E 256
#define H 512
#define V 10000
#define S 100

typedef float f4 __attribute__((ext_vector_type(4)));

// ---- workspace float offsets ----
#define OFF_ENCP 0                          // [32][800][512]
#define OFF_GP   (OFF_ENCP + B*T*512)       // [4][32][2048] gates partials (kq-major)
#define OFF_ZB   (OFF_GP + 4*B*2048)        // [32][512] z
#define OFF_CB   (OFF_ZB + B*512)           // [32][512] ctx
#define OFF_DECC (OFF_CB + B*512)           // [2][32][512] cell parity
#define OFF_QV   (OFF_DECC + 2*B*512)       // [32][512]
#define OFF_PB   (OFF_QV + B*512)           // [32][800] p = exp(e)
#define OFF_PSL  (OFF_PB + B*800)           // [32][8] slice sums
#define OFF_CP   (OFF_PSL + B*8)            // [32][8][512] ctx partials
#define OFF_YC   (OFF_CP + B*8*512)         // [32][1024] [z | ctx]
#define OFF_KEY  (OFF_YC + B*1024)          // [2][32] u64 packed (mono(lmax), ~idx)
#define OFF_ESUM (OFF_KEY + 128)            // [2][32] sum exp(l)

__device__ __forceinline__ float tanh_fast(float x) {
    float e = __expf(2.0f * x);
    return 1.0f - __fdividef(2.0f, e + 1.0f);
}

// enc_proj = enc_pad @ W_enc (once)
__global__ __launch_bounds__(256) void k_encproj(const float* Ap, const float* Wenc, float* outp) {
    __shared__ float Ast[16][68];
    __shared__ float Bs[16][68];
    int rb = blockIdx.x, cb = blockIdx.y;
    int tid = threadIdx.x;
    int tx = tid & 15, ty = tid >> 4;
    float acc[4][4] = {};
    for (int kb = 0; kb < 32; kb++) {
        #pragma unroll
        for (int i = 0; i < 4; i++) {
            int idx = tid + i*256;
            int r = idx >> 4, k = idx & 15;
            Ast[k][r] = Ap[(rb*64 + r)*512 + kb*16 + k];
        }
        #pragma unroll
        for (int i = 0; i < 4; i++) {
            int idx = tid + i*256;
            int k = idx >> 6, c = idx & 63;
            Bs[k][c] = Wenc[(kb*16 + k)*512 + cb*64 + c];
        }
        __syncthreads();
        #pragma unroll
        for (int kk = 0; kk < 16; kk++) {
            f4 a4 = *(const f4*)&Ast[kk][ty*4];
            f4 b4 = *(const f4*)&Bs[kk][tx*4];
            #pragma unroll
            for (int i = 0; i < 4; i++)
                #pragma unroll
                for (int j = 0; j < 4; j++)
                    acc[i][j] += a4[i] * b4[j];
        }
        __syncthreads();
    }
    #pragma unroll
    for (int i = 0; i < 4; i++)
        #pragma unroll
        for (int j = 0; j < 4; j++)
            outp[(rb*64 + ty*4 + i)*512 + cb*64 + tx*4 + j] = acc[i][j];
}

__global__ __launch_bounds__(512) void k_init(float* ws) {
    int idx = blockIdx.x*512 + threadIdx.x;   // 32 blocks -> 16384
    ws[OFF_ZB + idx] = 0.f;
    ws[OFF_CB + idx] = 0.f;
    ws[OFF_DECC + B*512 + idx] = 0.f;         // decc[1]
    if (blockIdx.x == 0 && threadIdx.x < 32) {
        unsigned long long* key = (unsigned long long*)(ws + OFF_KEY);
        key[32 + threadIdx.x] = 0xFFFFFFFEull;   // slot[1]: pred = BOS = 1
    }
}

// K0: gates partials. grid (64 j-tiles, 4 k-quarters), 512 thr, 75KB LDS (2 blk/CU).
__global__ __launch_bounds__(512, 2) void k0_gates(const float* __restrict__ Wih,
    const float* __restrict__ Whh, const float* __restrict__ emb,
    float* __restrict__ ws, float* __restrict__ outp, int s) {
    __shared__ float xs[32*324];
    __shared__ float part[8*32*33];
    __shared__ int preds[32];
    const int tid = threadIdx.x;
    const int jt = blockIdx.x, kq = blockIdx.y;
    const int p = s & 1;
    unsigned long long* keys = (unsigned long long*)(ws + OFF_KEY);
    float* esum = ws + OFF_ESUM;
    if (tid < 32) {
        unsigned long long k = keys[(p^1)*32 + tid];
        int pr = (int)(0xFFFFFFFFu - (unsigned)(k & 0xFFFFFFFFull));
        preds[tid] = pr;
        if (jt == 0 && kq == 0) {
            if (s > 0) {
                unsigned mu = (unsigned)(k >> 32);
                unsigned ou = (mu & 0x80000000u) ? (mu & 0x7FFFFFFFu) : ~mu;
                outp[tid*S + (s-1)] = __uint_as_float(ou) - logf(esum[(p^1)*32 + tid]);
                outp[B*S + tid*S + (s-1)] = (float)pr;
            }
            keys[p*32 + tid] = 0ull;
            esum[p*32 + tid] = 0.f;
        }
    }
    __syncthreads();
    const float* cbuf = ws + OFF_CB;
    const float* zbuf = ws + OFF_ZB;
    // stage x quarter [32][320] (stride 324)
    #pragma unroll
    for (int i = 0; i < 5; i++) {
        int idx = tid + i*512;                // < 2560
        int b = idx / 80, c4 = idx - b*80;
        int k = kq*320 + c4*4;
        f4 v;
        if (k < 256)      v = *(const f4*)&emb[(size_t)preds[b]*E + k];
        else if (k < 768) v = *(const f4*)&cbuf[b*512 + (k-256)];
        else              v = *(const f4*)&zbuf[b*512 + (k-768)];
        *(f4*)&xs[b*324 + c4*4] = v;
    }
    __syncthreads();
    const int wid = tid >> 6, l = tid & 63;
    const int j0 = (l >> 3)*4, b0 = (l & 7)*4;
    const int ks0 = wid*40;
    float acc[4][4] = {};
    #pragma unroll 2
    for (int it = 0; it < 10; it++) {
        int k = ks0 + it*4;
        int kk = kq*320 + k;
        f4 w[4];
        if (kk < 768) {
            #pragma unroll
            for (int i = 0; i < 4; i++)
                w[i] = *(const f4*)&Wih[(size_t)(jt*32 + j0 + i)*768 + kk];
        } else {
            #pragma unroll
            for (int i = 0; i < 4; i++)
                w[i] = *(const f4*)&Whh[(size_t)(jt*32 + j0 + i)*512 + (kk - 768)];
        }
        f4 x[4];
        #pragma unroll
        for (int j = 0; j < 4; j++) x[j] = *(const f4*)&xs[(b0 + j)*324 + k];
        #pragma unroll
        for (int i = 0; i < 4; i++)
            #pragma unroll
            for (int j = 0; j < 4; j++)
                acc[i][j] += w[i][0]*x[j][0] + w[i][1]*x[j][1]
                           + w[i][2]*x[j][2] + w[i][3]*x[j][3];
    }
    __syncthreads();
    #pragma unroll
    for (int i = 0; i < 4; i++)
        #pragma unroll
        for (int j = 0; j < 4; j++)
            part[wid*1056 + (j0 + i)*33 + (b0 + j)] = acc[i][j];
    __syncthreads();
    #pragma unroll
    for (int u = 0; u < 2; u++) {
        int o = tid + u*512;                  // < 1024
        int j = o >> 5, b = o & 31;
        float g = 0.f;
        #pragma unroll
        for (int w2 = 0; w2 < 8; w2++) g += part[w2*1056 + j*33 + b];
        ws[OFF_GP + (kq*32 + b)*2048 + jt*32 + j] = g;
    }
}

// K12: LSTM pointwise + q[b] = z[b] @ W_dec. 32 blocks (one per b).
__global__ __launch_bounds__(512) void k12_lstmq(const float* __restrict__ Wdec,
    const float* __restrict__ bih, const float* __restrict__ bhh,
    float* __restrict__ ws, int s) {
    __shared__ float zs[516];
    __shared__ float pq[4*516];
    const int tid = threadIdx.x, b = blockIdx.x;
    const int p = s & 1;
    const float* dold = ws + OFF_DECC + (p^1)*B*512;
    float* dnew = ws + OFF_DECC + p*B*512;
    {
        int h = tid;
        float gv[4];
        #pragma unroll
        for (int g = 0; g < 4; g++) {
            float sacc = bih[g*512 + h] + bhh[g*512 + h];
            #pragma unroll
            for (int kc = 0; kc < 4; kc++)
                sacc += ws[OFF_GP + (kc*32 + b)*2048 + g*512 + h];
            gv[g] = sacc;
        }
        float ig = 1.f/(1.f + expf(-gv[0]));
        float fg = 1.f/(1.f + expf(-gv[1]));
        float g2 = tanhf(gv[2]);
        float og = 1.f/(1.f + expf(-gv[3]));
        float c = fg*dold[b*512 + h] + ig*g2;
        dnew[b*512 + h] = c;
        float z = og*tanhf(c);
        zs[h] = z;
        ws[OFF_ZB + b*512 + h] = z;
        ws[OFF_YC + b*1024 + h] = z;
    }
    __syncthreads();
    {
        const int aq = tid & 127, ks = tid >> 7;
        const int a0 = aq*4;
        f4 accq = {0.f, 0.f, 0.f, 0.f};
        #pragma unroll 4
        for (int kk = 0; kk < 128; kk += 4) {
            int k = ks*128 + kk;
            f4 z4 = *(const f4*)&zs[k];
            f4 w0 = *(const f4*)&Wdec[(size_t)(k+0)*512 + a0];
            f4 w1 = *(const f4*)&Wdec[(size_t)(k+1)*512 + a0];
            f4 w2 = *(const f4*)&Wdec[(size_t)(k+2)*512 + a0];
            f4 w3 = *(const f4*)&Wdec[(size_t)(k+3)*512 + a0];
            accq += z4[0]*w0 + z4[1]*w1 + z4[2]*w2 + z4[3]*w3;
        }
        *(f4*)&pq[ks*516 + a0] = accq;
    }
    __syncthreads();
    {
        int a = tid;
        float q = pq[a] + pq[516 + a] + pq[2*516 + a] + pq[3*516 + a];
        ws[OFF_QV + b*512 + a] = q;
    }
}

// K34: e -> p (slice) + ctx partials for slice. 256 blocks = b*8 + ts.
__global__ __launch_bounds__(512, 2) void k34_ectx(const float* __restrict__ encpad,
    const float* __restrict__ vatt, const int* __restrict__ enclen,
    float* __restrict__ ws) {
    __shared__ float qs[512];
    __shared__ float vs[512];
    __shared__ float pl[104];
    __shared__ float wp[8];
    const int tid = threadIdx.x;
    const int b = blockIdx.x >> 3, ts = blockIdx.x & 7;
    const int len = enclen[b];
    const int t0 = ts*100;
    const int tend = min(t0 + 100, len);
    qs[tid] = ws[OFF_QV + b*512 + tid];
    vs[tid] = vatt[tid];
    if (tid < 100) { pl[tid] = 0.f; ws[OFF_PB + b*800 + t0 + tid] = 0.f; }
    if (tid < 8) wp[tid] = 0.f;
    __syncthreads();
    const int wid = tid >> 6, lane = tid & 63;
    const f4* encp4 = (const f4*)(ws + OFF_ENCP);
    float psum = 0.f;
    for (int t = t0 + wid; t < tend; t += 8) {
        const f4* row = &encp4[(size_t)(b*800 + t)*128];
        float accd = 0.f;
        #pragma unroll
        for (int i = 0; i < 2; i++) {
            int u = lane + 64*i;
            f4 ep = row[u];
            f4 q4 = *(const f4*)&qs[4*u];
            f4 vv = *(const f4*)&vs[4*u];
            accd += tanh_fast(ep[0]+q4[0])*vv[0];
            accd += tanh_fast(ep[1]+q4[1])*vv[1];
            accd += tanh_fast(ep[2]+q4[2])*vv[2];
            accd += tanh_fast(ep[3]+q4[3])*vv[3];
        }
        #pragma unroll
        for (int off = 32; off >= 1; off >>= 1) accd += __shfl_xor(accd, off, 64);
        if (lane == 0) {
            float pv = __expf(accd);
            pl[t - t0] = pv;
            ws[OFF_PB + b*800 + t] = pv;
            psum += pv;
        }
    }
    if (lane == 0 && tend > t0) wp[wid] = psum;
    __syncthreads();
    if (tid == 0) {
        float sacc = 0.f;
        #pragma unroll
        for (int i = 0; i < 8; i++) sacc += wp[i];
        ws[OFF_PSL + b*8 + ts] = sacc;
    }
    // ctx partial for this t-slice: all 512 d in parallel
    {
        const int nt = tend - t0;
        float accd = 0.f;
        const float* ebase = &encpad[((size_t)(b*800 + t0))*512 + tid];
        for (int tt = 0; tt < nt; tt++)
            accd += pl[tt] * ebase[(size_t)tt*512];
        ws[OFF_CP + (b*8 + ts)*512 + tid] = accd;
    }
}

// K4b: ctx reduce + attention-weight output. 32 blocks (b).
__global__ __launch_bounds__(512) void k4b_ctxw(float* __restrict__ ws,
    float* __restrict__ outp, int s) {
    const int tid = threadIdx.x, b = blockIdx.x;
    __shared__ float invs;
    if (tid == 0) {
        float sacc = 0.f;
        #pragma unroll
        for (int i = 0; i < 8; i++) sacc += ws[OFF_PSL + b*8 + i];
        invs = 1.f / sacc;
    }
    __syncthreads();
    float inv = invs;
    {
        int d = tid;
        float c = 0.f;
        #pragma unroll
        for (int t2 = 0; t2 < 8; t2++) c += ws[OFF_CP + (b*8 + t2)*512 + d];
        c *= inv;
        ws[OFF_YC + b*1024 + 512 + d] = c;
        ws[OFF_CB + b*512 + d] = c;
    }
    float* wrow = outp + 2*B*S + (size_t)(b*S + s)*T;
    for (int t = tid; t < 800; t += 512)
        wrow[t] = ws[OFF_PB + b*800 + t] * inv;
}

// K5: logits (40 v-rows x 32 b per block, 250 blocks) + fused argmax/sumexp atomics.
__global__ __launch_bounds__(512) void k5_logits(const float* __restrict__ Wout,
    const float* __restrict__ bout, float* __restrict__ ws, int s) {
    __shared__ float sm[32*1028];
    const int tid = threadIdx.x, blk = blockIdx.x;
    const int p = s & 1;
    const int v0 = blk*40;
    for (int i = 0; i < 17; i++) {
        int q = tid + i*512;
        if (q < 8192) {
            int b = q >> 8, qq = q & 255;
            *(f4*)&sm[b*1028 + qq*4] = *(const f4*)&ws[OFF_YC + b*1024 + qq*4];
        }
    }
    __syncthreads();
    const int wid = tid >> 6, l = tid & 63;
    const int vq = l & 7, bq2 = l >> 3;
    float acc[5][4] = {};
    const int kb = wid*128;
    const float* wbase = &Wout[(size_t)(v0 + vq*5)*1024 + kb];
    #pragma unroll 2
    for (int g = 0; g < 32; g++) {
        f4 w[5];
        #pragma unroll
        for (int i = 0; i < 5; i++) w[i] = *(const f4*)&wbase[i*1024 + g*4];
        #pragma unroll
        for (int j = 0; j < 4; j++) {
            f4 x4 = *(const f4*)&sm[(bq2+8*j)*1028 + kb + g*4];
            #pragma unroll
            for (int i = 0; i < 5; i++)
                acc[i][j] += w[i][0]*x4[0] + w[i][1]*x4[1] + w[i][2]*x4[2] + w[i][3]*x4[3];
        }
    }
    __syncthreads();
    #pragma unroll
    for (int i = 0; i < 5; i++)
        #pragma unroll
        for (int j = 0; j < 4; j++)
            sm[wid*1320 + (vq*5+i)*33 + (bq2+8*j)] = acc[i][j];
    __syncthreads();
    if (tid < 256) {
        int b = tid >> 3, u = tid & 7;
        float bmax = -3.0e38f; int bidx = 0; float bsum = 0.f;
        #pragma unroll
        for (int i = 0; i < 5; i++) {
            int r = u*5 + i;
            float lv = bout[v0 + r];
            #pragma unroll
            for (int w2 = 0; w2 < 8; w2++) lv += sm[w2*1320 + r*33 + b];
            bsum += __expf(lv);
            if (lv > bmax) { bmax = lv; bidx = v0 + r; }
        }
        #pragma unroll
        for (int off = 1; off < 8; off <<= 1) {
            float ov = __shfl_xor(bmax, off, 64);
            int oi = __shfl_xor(bidx, off, 64);
            float os = __shfl_xor(bsum, off, 64);
            bsum += os;
            if (ov > bmax || (ov == bmax && oi < bidx)) { bmax = ov; bidx = oi; }
        }
        if (u == 0) {
            unsigned mu = __float_as_uint(bmax);
            mu = (mu & 0x80000000u) ? ~mu : (mu | 0x80000000u);
            unsigned long long kk = ((unsigned long long)mu << 32)
                                  | (unsigned long long)(0xFFFFFFFFu - (unsigned)bidx);
            atomicMax((unsigned long long*)(ws + OFF_KEY) + p*32 + b, kk);
            atomicAdd(ws + OFF_ESUM + p*32 + b, bsum);
        }
    }
}

__global__ __launch_bounds__(64) void k_final(float* __restrict__ ws, float* __restrict__ outp) {
    int b = threadIdx.x;
    if (b < 32) {
        unsigned long long k = ((unsigned long long*)(ws + OFF_KEY))[32 + b];  // p(99)=1
        unsigned mu = (unsigned)(k >> 32);
        unsigned ou = (mu & 0x80000000u) ? (mu & 0x7FFFFFFFu) : ~mu;
        int pr = (int)(0xFFFFFFFFu - (unsigned)(k & 0xFFFFFFFFull));
        outp[b*S + 99] = __uint_as_float(ou) - logf(ws[OFF_ESUM + 32 + b]);
        outp[B*S + b*S + 99] = (float)pr;
    }
}

extern "C" void kernel_launch(void* const* d_in, const int* in_sizes, int n_in,
                              void* d_out, int out_size, void* d_ws, size_t ws_size,
                              hipStream_t stream) {
    (void)in_sizes; (void)n_in; (void)out_size; (void)ws_size;
    const float* encpad = (const float*)d_in[0];
    const float* emb    = (const float*)d_in[1];
    const float* Wih    = (const float*)d_in[2];
    const float* Whh    = (const float*)d_in[3];
    const float* bih    = (const float*)d_in[4];
    const float* bhh    = (const float*)d_in[5];
    const float* Wenc   = (const float*)d_in[6];
    const float* Wdec   = (const float*)d_in[7];
    const float* vatt   = (const float*)d_in[8];
    const float* Wout   = (const float*)d_in[9];
    const float* bout   = (const float*)d_in[10];
    const int*   enclen = (const int*)d_in[11];
    float* outp = (float*)d_out;
    float* ws   = (float*)d_ws;

    k_init<<<32, 512, 0, stream>>>(ws);
    k_encproj<<<dim3(400, 8), 256, 0, stream>>>(encpad, Wenc, ws + OFF_ENCP);

    for (int s = 0; s < S; s++) {
        k0_gates<<<dim3(64, 4), 512, 0, stream>>>(Wih, Whh, emb, ws, outp, s);
        k12_lstmq<<<32, 512, 0, stream>>>(Wdec, bih, bhh, ws, s);
        k34_ectx<<<256, 512, 0, stream>>>(encpad, vatt, enclen, ws);
        k4b_ctxw<<<32, 512, 0, stream>>>(ws, outp, s);
        k5_logits<<<250, 512, 0, stream>>>(Wout, bout, ws, s);
    }
    k_final<<<1, 64, 0, stream>>>(ws, outp);
}